// Round 8
// baseline (1837.795 us; speedup 1.0000x reference)
//
#include <hip/hip_runtime.h>
#include <hip/hip_cooperative_groups.h>

namespace cg = cooperative_groups;

// GPR-GNN: out = b_fc + sum_k temp[k] * A_hat^k (MLP(x) @ W_fc)
// Trick 1: project features to scalar BEFORE propagation (linearity) -> 1 float/node.
// Trick 2: gather-based hops; per-edge GLOBAL atomics cost ~35B memory-side RMW
//          (measured R2/R3) -> per-edge atomics are LDS-only.
// Trick 3: u-space propagation u_k = D^{-1/2} z_k -> per-edge work is one
//          unweighted gather+add; CSR is row indices only.
// Trick 4: CSR build = two-level counting sort (98 super-buckets of 1024 nodes;
//          pass-1 runs ~600B >> 128B line -> write amp ~1; pass-2 scatters in
//          one bucket's ~137KB L2-resident window).
// Trick 5: 2-phase unrolled gathers (4 indices then 4 values in flight) for
//          latency-bound loops (R7: VALUBusy ~0.4%).
// Trick 6 (R8): ~half of the 340us wall was ~14 launch gaps (kernels sum to
//          ~170us) -> fuse EVERYTHING into one cooperative kernel, grid.sync
//          between phases. Persistent node ownership in the hop phase keeps
//          rs/re/nrm and the out-accumulator in registers across all 10 hops.

#define NBLK 256           // 1 block/CU -> co-residency guaranteed
#define NTHR 1024
#define SBSH 10            // 1024 nodes per super-bucket
#define CAP1 34304         // super-bucket capacity (mean ~32653, ~9 sigma pad)
#define EPT  13            // edges per thread in pass 1
#define CH   (NTHR * EPT)  // 13312 edges per scatter chunk -> 241 chunks < 256

__global__ void __launch_bounds__(NTHR, 4)
k_fused(const float* __restrict__ x, const int* __restrict__ erow,
        const int* __restrict__ ecol,
        const float* __restrict__ W1, const float* __restrict__ b1,
        const float* __restrict__ W2, const float* __restrict__ b2,
        const float* __restrict__ temp, const float* __restrict__ Wfc,
        const float* __restrict__ bfc,
        int* __restrict__ bcursor, unsigned int* __restrict__ ebuf1,
        unsigned int* __restrict__ csr, int2* __restrict__ rs_re,
        float2* __restrict__ nrm, float* __restrict__ dinv,
        float* __restrict__ zarr, float* __restrict__ u0,
        float* __restrict__ u1, float* __restrict__ out,
        int n, int e, int K, int nsb) {
    cg::grid_group grid = cg::this_grid();
    __shared__ int hist[1024];
    __shared__ int base[128];
    __shared__ int wsum[16];

    const int t = threadIdx.x;
    const int b = blockIdx.x;

    // ---- phase 0: zero bucket cursors (ws is poisoned each launch) ----
    if (b == 0 && t < 128) bcursor[t] = 0;
    grid.sync();

    // ---- phase 1: scatter edges into 98 super-buckets ----
    {
        int s = b * CH;
        if (s < e) {
            if (t < 128) hist[t] = 0;
            __syncthreads();
            int r[EPT], c[EPT];
#pragma unroll
            for (int j = 0; j < EPT; j++) {
                int i = s + j * NTHR + t;
                bool ok = (i < e);
                c[j] = ok ? ecol[i] : -1;
                r[j] = ok ? erow[i] : 0;
                if (ok) atomicAdd(&hist[c[j] >> SBSH], 1);
            }
            __syncthreads();
            if (t < nsb) {
                int cc = hist[t];
                base[t] = cc ? atomicAdd(&bcursor[t], cc) : 0;
                hist[t] = 0;    // reuse as local cursor
            }
            __syncthreads();
#pragma unroll
            for (int j = 0; j < EPT; j++) {
                if (c[j] >= 0) {
                    int bb = c[j] >> SBSH;
                    int pos = base[bb] + atomicAdd(&hist[bb], 1);
                    if (pos < CAP1)
                        ebuf1[(size_t)bb * CAP1 + pos] =
                            ((unsigned int)r[j] << SBSH) |
                            (unsigned int)(c[j] & ((1 << SBSH) - 1));
                }
            }
        }
        __threadfence();
        grid.sync();
    }

    // ---- phase 2: per-bucket CSR build (blocks 0..nsb-1) ----
    if (b < nsb) {
        hist[t] = 0;
        __syncthreads();
        int cnt = min(bcursor[b], CAP1);
        size_t g = (size_t)b * CAP1;
        int last = cnt > 0 ? cnt - 1 : 0;
        for (int j = t; j < cnt; j += 4096) {
            int j1 = j + 1024, j2 = j + 2048, j3 = j + 3072;
            unsigned int p0 = ebuf1[g + j];
            unsigned int p1 = ebuf1[g + min(j1, last)];
            unsigned int p2 = ebuf1[g + min(j2, last)];
            unsigned int p3 = ebuf1[g + min(j3, last)];
            atomicAdd(&hist[p0 & 1023], 1);
            if (j1 < cnt) atomicAdd(&hist[p1 & 1023], 1);
            if (j2 < cnt) atomicAdd(&hist[p2 & 1023], 1);
            if (j3 < cnt) atomicAdd(&hist[p3 & 1023], 1);
        }
        __syncthreads();

        int deg = hist[t];
        int lane = t & 63, w = t >> 6;
        int v = deg;
#pragma unroll
        for (int o = 1; o < 64; o <<= 1) {
            int u = __shfl_up(v, o);
            if (lane >= o) v += u;
        }
        if (lane == 63) wsum[w] = v;
        __syncthreads();
        if (w == 0) {
            int sv = (lane < 16) ? wsum[lane] : 0;
#pragma unroll
            for (int o = 1; o < 16; o <<= 1) {
                int u = __shfl_up(sv, o);
                if (lane >= o) sv += u;
            }
            if (lane < 16) wsum[lane] = sv;
        }
        __syncthreads();
        int excl = v - deg + (w > 0 ? wsum[w - 1] : 0);

        int node = (b << SBSH) + t;
        if (node < n) {
            int bs = (int)g + excl;
            rs_re[node] = make_int2(bs, bs + deg);
            float d = (float)(deg + 1);     // +1 self-loop
            float di = rsqrtf(d);
            dinv[node] = di;
            nrm[node] = make_float2(di * di, d * di);   // {dinv2, sqrt(d)}
        }
        __syncthreads();
        hist[t] = excl;                      // per-sub cursor
        __syncthreads();
        for (int j = t; j < cnt; j += 4096) {
            int j1 = j + 1024, j2 = j + 2048, j3 = j + 3072;
            unsigned int p0 = ebuf1[g + j];
            unsigned int p1 = ebuf1[g + min(j1, last)];
            unsigned int p2 = ebuf1[g + min(j2, last)];
            unsigned int p3 = ebuf1[g + min(j3, last)];
            int pos0 = atomicAdd(&hist[p0 & 1023], 1);
            csr[g + pos0] = p0 >> SBSH;
            if (j1 < cnt) { int p = atomicAdd(&hist[p1 & 1023], 1); csr[g + p] = p1 >> SBSH; }
            if (j2 < cnt) { int p = atomicAdd(&hist[p2 & 1023], 1); csr[g + p] = p2 >> SBSH; }
            if (j3 < cnt) { int p = atomicAdd(&hist[p3 & 1023], 1); csr[g + p] = p3 >> SBSH; }
        }
    }
    __threadfence();
    grid.sync();

    // ---- phase 3: MLP + projection, wave per node (grid-stride) ----
    {
        int gw = (b * NTHR + t) >> 6;        // global wave id (4096 waves)
        int lane = t & 63;
        float b2l = b2[lane];
        float wfl = Wfc[lane];
        for (int node = gw; node < n; node += NBLK * (NTHR / 64)) {
            float xv = x[node];
            float acc = b2l;
#pragma unroll
            for (int j = 0; j < 32; j++) {
                float h1 = fmaxf(fmaf(xv, W1[j], b1[j]), 0.f);
                acc = fmaf(h1, W2[j * 64 + lane], acc);
            }
            float c = fmaxf(acc, 0.f) * wfl;
#pragma unroll
            for (int o = 32; o >= 1; o >>= 1) c += __shfl_xor(c, o);
            if (lane == 0) {
                zarr[node] = c;
                u0[node] = dinv[node] * c;
            }
        }
    }
    __threadfence();
    grid.sync();

    // ---- phase 4: K hops, 2 threads per node, persistent ownership ----
    {
        int slot = b * NTHR + t;
        int node = slot >> 1;
        int sub = slot & 1;
        bool act = (node < n);
        int s = 0, en = 0;
        float2 nv = make_float2(0.f, 0.f);
        float out_acc = 0.f;
        if (act) {
            int2 se = rs_re[node];
            s = se.x; en = se.y;
            nv = nrm[node];
            if (sub == 0) out_acc = fmaf(temp[0], zarr[node], bfc[0]);
        }
        float* up = u0;
        float* uc = u1;
        for (int k = 1; k <= K; k++) {
            float tk = temp[k];
            float sum = 0.f;
            if (act) {
                sum = (sub == 0) ? up[node] : 0.f;   // self-loop
                for (int i = s + sub; i < en; i += 8) {
                    int j1 = i + 2, j2 = i + 4, j3 = i + 6;
                    unsigned int a0 = csr[i];
                    unsigned int a1 = (j1 < en) ? csr[j1] : 0u;
                    unsigned int a2 = (j2 < en) ? csr[j2] : 0u;
                    unsigned int a3 = (j3 < en) ? csr[j3] : 0u;
                    float v0 = up[a0];
                    float v1 = up[a1];
                    float v2 = up[a2];
                    float v3 = up[a3];
                    v1 = (j1 < en) ? v1 : 0.f;
                    v2 = (j2 < en) ? v2 : 0.f;
                    v3 = (j3 < en) ? v3 : 0.f;
                    sum += (v0 + v1) + (v2 + v3);
                }
            }
            sum += __shfl_xor(sum, 1);
            if (act && sub == 0) {
                float u = nv.x * sum;
                if (k < K) uc[node] = u;
                out_acc = fmaf(tk * nv.y, u, out_acc);
            }
            if (k < K) {
                __threadfence();
                grid.sync();
            }
            float* tmp = up; up = uc; uc = tmp;
        }
        if (act && sub == 0) out[node] = out_acc;
    }
}

static inline size_t align256(size_t v) { return (v + 255) & ~(size_t)255; }

extern "C" void kernel_launch(void* const* d_in, const int* in_sizes, int n_in,
                              void* d_out, int out_size, void* d_ws, size_t ws_size,
                              hipStream_t stream) {
    const float* x    = (const float*)d_in[0];
    const int*   ei   = (const int*)d_in[1];
    const float* W1   = (const float*)d_in[2];
    const float* b1   = (const float*)d_in[3];
    const float* W2   = (const float*)d_in[4];
    const float* b2   = (const float*)d_in[5];
    const float* temp = (const float*)d_in[6];
    const float* Wfc  = (const float*)d_in[7];
    const float* bfc  = (const float*)d_in[8];

    int n = in_sizes[0];        // 100000 nodes
    int e = in_sizes[1] / 2;    // 3.2M edges
    int K = in_sizes[6] - 1;    // 10 hops
    int nsb = (n + (1 << SBSH) - 1) >> SBSH;   // 98 super-buckets

    const int* erow = ei;             // edge_index[0] = source
    const int* ecol = ei + e;         // edge_index[1] = target

    float* out = (float*)d_out;

    // workspace carve
    char* ws = (char*)d_ws;
    int*          bcursor = (int*)ws;          ws += align256((size_t)128 * 4);
    unsigned int* ebuf1   = (unsigned int*)ws; ws += align256((size_t)nsb * CAP1 * 4);
    unsigned int* csr     = (unsigned int*)ws; ws += align256((size_t)nsb * CAP1 * 4);
    int2*         rs_re   = (int2*)ws;         ws += align256((size_t)n * 8);
    float2*       nrm     = (float2*)ws;       ws += align256((size_t)n * 8);
    float*        dinv    = (float*)ws;        ws += align256((size_t)n * 4);
    float*        zarr    = (float*)ws;        ws += align256((size_t)n * 4);
    float*        u0      = (float*)ws;        ws += align256((size_t)n * 4);
    float*        u1      = (float*)ws;        ws += align256((size_t)n * 4);

    void* args[] = {
        (void*)&x, (void*)&erow, (void*)&ecol,
        (void*)&W1, (void*)&b1, (void*)&W2, (void*)&b2,
        (void*)&temp, (void*)&Wfc, (void*)&bfc,
        (void*)&bcursor, (void*)&ebuf1, (void*)&csr, (void*)&rs_re,
        (void*)&nrm, (void*)&dinv, (void*)&zarr, (void*)&u0, (void*)&u1,
        (void*)&out, (void*)&n, (void*)&e, (void*)&K, (void*)&nsb
    };
    hipLaunchCooperativeKernel((const void*)k_fused, dim3(NBLK), dim3(NTHR),
                               args, 0, stream);
}

// Round 9
// 334.644 us; speedup vs baseline: 5.4918x; 5.4918x over previous
//
#include <hip/hip_runtime.h>

// GPR-GNN: out = b_fc + sum_k temp[k] * A_hat^k (MLP(x) @ W_fc)
// Trick 1: project features to scalar BEFORE propagation (linearity) -> 1 float/node.
// Trick 2: gather-based hops; per-edge GLOBAL atomics cost ~35B memory-side RMW
//          (measured R2/R3) -> per-edge atomics are LDS-only.
// Trick 3: u-space propagation u_k = D^{-1/2} z_k -> per-edge work is one
//          unweighted gather+add; CSR is row indices only.
// Trick 4: CSR build = two-level counting sort (98 super-buckets of 1024 nodes;
//          pass-1 runs ~600B >> 128B line -> write amp ~1; pass-2 scatters in
//          one bucket's L2-resident window).
// Trick 5: segments padded to x4 entries; pad entries index a dummy slot n with
//          u[n]=0 -> hop does ONE aligned uint4 index load + 4 independent
//          gathers per thread, no masking (latency chain cut 4x).
// Trick 6: MLP fused into k_scatter tail (independent of CSR); u0/out init
//          fused into k_sub. 13 launches.
// ANTI-LESSON (R8, measured): cooperative grid.sync costs ~125us each on the
//          8-XCD MI355X (device-scope fence = cross-XCD L2 writeback storm);
//          kernel launch boundaries are far cheaper. Do NOT fuse via grid.sync.

#define TPB  256
#define SBSH 10            // 1024 nodes per super-bucket
#define CAP1 37376         // capacity: mean padded ~34189, ~16 sigma; mult of 4
#define EPT  16            // edges per thread in pass 1
#define CH   (TPB * EPT)   // 4096 edges per scatter block

__global__ void k_zero(int* __restrict__ bcursor, int nsb) {
    int i = blockIdx.x * blockDim.x + threadIdx.x;
    if (i < nsb) bcursor[i] = 0;
}

// Pass 1: read 16 edges/thread into registers (one coalesced pass), LDS
// histogram over 98 buckets, one reservation atomic per (block,bucket),
// place packed (row<<10)|(col&1023). Then: fused MLP+projection z = MLP(x).Wfc
// (independent of the CSR; wave per node, grid-stride).
__global__ void k_scatter(const int* __restrict__ erow, const int* __restrict__ ecol,
                          int* __restrict__ bcursor, unsigned int* __restrict__ ebuf1,
                          const float* __restrict__ x, const float* __restrict__ W1,
                          const float* __restrict__ b1, const float* __restrict__ W2,
                          const float* __restrict__ b2, const float* __restrict__ Wfc,
                          float* __restrict__ zarr, int e, int n, int nsb) {
    __shared__ int hist[128];
    __shared__ int base[128];
    int t = threadIdx.x;
    int s = blockIdx.x * CH;
    int r[EPT], c[EPT];

    if (t < 128) hist[t] = 0;
    __syncthreads();
#pragma unroll
    for (int j = 0; j < EPT; j++) {
        int i = s + j * TPB + t;
        bool ok = (i < e);
        c[j] = ok ? ecol[i] : -1;
        r[j] = ok ? erow[i] : 0;
        if (ok) atomicAdd(&hist[c[j] >> SBSH], 1);
    }
    __syncthreads();
    if (t < nsb) {
        int cc = hist[t];
        base[t] = cc ? atomicAdd(&bcursor[t], cc) : 0;
        hist[t] = 0;    // reuse as local cursor
    }
    __syncthreads();
#pragma unroll
    for (int j = 0; j < EPT; j++) {
        if (c[j] >= 0) {
            int b = c[j] >> SBSH;
            int pos = base[b] + atomicAdd(&hist[b], 1);
            if (pos < CAP1)
                ebuf1[(size_t)b * CAP1 + pos] =
                    ((unsigned int)r[j] << SBSH) | (unsigned int)(c[j] & ((1 << SBSH) - 1));
        }
    }

    // ---- fused MLP + projection (no barrier needed; independent data) ----
    int gw = (blockIdx.x * TPB + t) >> 6;     // global wave id
    int nwaves = (gridDim.x * TPB) >> 6;
    int lane = t & 63;
    float b2l = b2[lane];
    float wfl = Wfc[lane];
    for (int node = gw; node < n; node += nwaves) {
        float xv = x[node];
        float acc = b2l;
#pragma unroll
        for (int j = 0; j < 32; j++) {
            float h1 = fmaxf(fmaf(xv, W1[j], b1[j]), 0.f);
            acc = fmaf(h1, W2[j * 64 + lane], acc);
        }
        float cz = fmaxf(acc, 0.f) * wfl;
#pragma unroll
        for (int o = 32; o >= 1; o >>= 1) cz += __shfl_xor(cz, o);
        if (lane == 0) zarr[node] = cz;
    }
}

// Pass 2: one 1024-thread block per super-bucket. LDS 1024-bin histogram,
// wave-shuffle scan over PADDED degrees (x4), scatter into the bucket's
// L2-resident window, pad entries -> dummy index n. Also emits per-node
// metadata and the fused u0/out initialization.
__global__ void __launch_bounds__(1024)
k_sub(const int* __restrict__ bcursor, const unsigned int* __restrict__ ebuf1,
      unsigned int* __restrict__ csr, int2* __restrict__ rs_re,
      float2* __restrict__ nrm, const float* __restrict__ zarr,
      const float* __restrict__ temp, const float* __restrict__ bfc,
      float* __restrict__ u0, float* __restrict__ u1,
      float* __restrict__ out, int n) {
    __shared__ int hist[1024];
    __shared__ int wsum[16];
    int b = blockIdx.x;
    int t = threadIdx.x;
    int lane = t & 63;
    int w = t >> 6;

    hist[t] = 0;
    __syncthreads();
    int cnt = min(bcursor[b], CAP1);
    size_t g = (size_t)b * CAP1;
    int last = cnt > 0 ? cnt - 1 : 0;
    for (int j = t; j < cnt; j += 4096) {
        int j1 = j + 1024, j2 = j + 2048, j3 = j + 3072;
        unsigned int p0 = ebuf1[g + j];
        unsigned int p1 = ebuf1[g + min(j1, last)];
        unsigned int p2 = ebuf1[g + min(j2, last)];
        unsigned int p3 = ebuf1[g + min(j3, last)];
        atomicAdd(&hist[p0 & 1023], 1);
        if (j1 < cnt) atomicAdd(&hist[p1 & 1023], 1);
        if (j2 < cnt) atomicAdd(&hist[p2 & 1023], 1);
        if (j3 < cnt) atomicAdd(&hist[p3 & 1023], 1);
    }
    __syncthreads();

    int deg = hist[t];
    int pdeg = (deg + 3) & ~3;          // padded to multiple of 4 (16B uint4)
    // inclusive scan of pdeg across 1024 threads
    int v = pdeg;
#pragma unroll
    for (int o = 1; o < 64; o <<= 1) {
        int u = __shfl_up(v, o);
        if (lane >= o) v += u;
    }
    if (lane == 63) wsum[w] = v;
    __syncthreads();
    if (w == 0) {
        int sv = (lane < 16) ? wsum[lane] : 0;
#pragma unroll
        for (int o = 1; o < 16; o <<= 1) {
            int u = __shfl_up(sv, o);
            if (lane >= o) sv += u;
        }
        if (lane < 16) wsum[lane] = sv;
    }
    __syncthreads();
    int pexcl = v - pdeg + (w > 0 ? wsum[w - 1] : 0);

    int node = (b << SBSH) + t;
    if (node < n) {
        int bs = (int)g + pexcl;
        rs_re[node] = make_int2(bs, bs + pdeg);
        float d = (float)(deg + 1);     // +1 self-loop
        float di = rsqrtf(d);
        nrm[node] = make_float2(di * di, d * di);   // {dinv2, sqrt(d)}
        // fused init: u0 = dinv * z ; out = b_fc + temp[0] * z
        float z = zarr[node];
        u0[node] = di * z;
        out[node] = fmaf(temp[0], z, bfc[0]);
    }
    if (b == 0 && t == 0) { u0[n] = 0.f; u1[n] = 0.f; }   // dummy gather slot
    __syncthreads();
    hist[t] = pexcl;                     // per-sub cursor
    __syncthreads();
    for (int j = t; j < cnt; j += 4096) {
        int j1 = j + 1024, j2 = j + 2048, j3 = j + 3072;
        unsigned int p0 = ebuf1[g + j];
        unsigned int p1 = ebuf1[g + min(j1, last)];
        unsigned int p2 = ebuf1[g + min(j2, last)];
        unsigned int p3 = ebuf1[g + min(j3, last)];
        int pos0 = atomicAdd(&hist[p0 & 1023], 1);
        csr[g + pos0] = p0 >> SBSH;
        if (j1 < cnt) { int p = atomicAdd(&hist[p1 & 1023], 1); csr[g + p] = p1 >> SBSH; }
        if (j2 < cnt) { int p = atomicAdd(&hist[p2 & 1023], 1); csr[g + p] = p2 >> SBSH; }
        if (j3 < cnt) { int p = atomicAdd(&hist[p3 & 1023], 1); csr[g + p] = p3 >> SBSH; }
    }
    __syncthreads();
    // pad fill: entries [pexcl+deg, pexcl+pdeg) -> dummy index n
    for (int p = pexcl + deg; p < pexcl + pdeg; p++)
        csr[g + p] = (unsigned int)n;
}

// Hop k: 8 threads/node. Thread sub loads ONE uint4 of indices (aligned:
// segments start at x4 entries) then 4 independent gathers; pads gather
// u[n]=0. u_k[c] = dinv2[c]*(u_{k-1}[c] + sum); out[c] += temp[k]*sqrt(d)*u_k.
__global__ void k_hop(const int2* __restrict__ rs_re, const uint4* __restrict__ csr4,
                      const float2* __restrict__ nrm,
                      const float* __restrict__ uprev, float* __restrict__ ucur,
                      float* __restrict__ out, const float* __restrict__ temp,
                      int k, int n, int is_last) {
    int tid = blockIdx.x * blockDim.x + threadIdx.x;
    int node = tid >> 3;
    int sub = tid & 7;
    if (node >= n) return;
    int2 se = rs_re[node];
    int s4 = se.x >> 2;                  // uint4 index of segment start
    int e4 = se.y >> 2;
    float sum = (sub == 0) ? uprev[node] : 0.f;   // self-loop term
    for (int i4 = s4 + sub; i4 < e4; i4 += 8) {
        uint4 a = csr4[i4];
        float v0 = uprev[a.x];
        float v1 = uprev[a.y];
        float v2 = uprev[a.z];
        float v3 = uprev[a.w];
        sum += (v0 + v1) + (v2 + v3);
    }
    sum += __shfl_xor(sum, 1);
    sum += __shfl_xor(sum, 2);
    sum += __shfl_xor(sum, 4);
    if (sub == 0) {
        float2 nv = nrm[node];           // {dinv2, sqrt(d)}
        float u = nv.x * sum;
        if (!is_last) ucur[node] = u;
        out[node] = fmaf(temp[k] * nv.y, u, out[node]);
    }
}

static inline size_t align256(size_t v) { return (v + 255) & ~(size_t)255; }

extern "C" void kernel_launch(void* const* d_in, const int* in_sizes, int n_in,
                              void* d_out, int out_size, void* d_ws, size_t ws_size,
                              hipStream_t stream) {
    const float* x    = (const float*)d_in[0];
    const int*   ei   = (const int*)d_in[1];
    const float* W1   = (const float*)d_in[2];
    const float* b1   = (const float*)d_in[3];
    const float* W2   = (const float*)d_in[4];
    const float* b2   = (const float*)d_in[5];
    const float* temp = (const float*)d_in[6];
    const float* Wfc  = (const float*)d_in[7];
    const float* bfc  = (const float*)d_in[8];

    const int n = in_sizes[0];        // 100000 nodes
    const int e = in_sizes[1] / 2;    // 3.2M edges
    const int K = in_sizes[6] - 1;    // 10 hops
    const int nsb = (n + (1 << SBSH) - 1) >> SBSH;   // 98 super-buckets

    const int* erow = ei;             // edge_index[0] = source
    const int* ecol = ei + e;         // edge_index[1] = target

    float* out = (float*)d_out;

    // workspace carve
    char* ws = (char*)d_ws;
    int*          bcursor = (int*)ws;          ws += align256((size_t)128 * 4);
    unsigned int* ebuf1   = (unsigned int*)ws; ws += align256((size_t)nsb * CAP1 * 4);
    unsigned int* csr     = (unsigned int*)ws; ws += align256((size_t)nsb * CAP1 * 4);
    int2*         rs_re   = (int2*)ws;         ws += align256((size_t)n * 8);
    float2*       nrm     = (float2*)ws;       ws += align256((size_t)n * 8);
    float*        zarr    = (float*)ws;        ws += align256((size_t)(n + 1) * 4);
    float*        u0      = (float*)ws;        ws += align256((size_t)(n + 1) * 4);
    float*        u1      = (float*)ws;        ws += align256((size_t)(n + 1) * 4);

    const int gS = (e + CH - 1) / CH;            // 782 scatter blocks
    const int gH = (8 * n + TPB - 1) / TPB;      // 8 threads/node hops

    k_zero<<<1, 128, 0, stream>>>(bcursor, nsb);
    k_scatter<<<gS, TPB, 0, stream>>>(erow, ecol, bcursor, ebuf1,
                                      x, W1, b1, W2, b2, Wfc, zarr, e, n, nsb);
    k_sub<<<nsb, 1024, 0, stream>>>(bcursor, ebuf1, csr, rs_re, nrm,
                                    zarr, temp, bfc, u0, u1, out, n);

    float* uin = u0;
    float* uout = u1;
    for (int k = 1; k <= K; k++) {
        k_hop<<<gH, TPB, 0, stream>>>(rs_re, (const uint4*)csr, nrm, uin, uout,
                                      out, temp, k, n, (k == K) ? 1 : 0);
        float* t2 = uin; uin = uout; uout = t2;
    }
}